// Round 1
// baseline (793.325 us; speedup 1.0000x reference)
//
#include <hip/hip_runtime.h>
#include <hip/hip_bf16.h>

#define LNUM 4
#define DIM  512
#define NH   8
#define DKH  256
#define DFFN 2048
#define SS   256
#define HDD  2048
#define TT   2048   // B*S tokens

typedef unsigned short ushort_t;
typedef __attribute__((ext_vector_type(8))) short bf16x8;
typedef __attribute__((ext_vector_type(4))) float f32x4;
typedef __attribute__((ext_vector_type(4))) unsigned short u16x4;

__device__ __forceinline__ ushort_t f2b(float f) {
  union { float f; unsigned u; } x; x.f = f;
  unsigned r = x.u + 0x7FFFu + ((x.u >> 16) & 1u);
  return (ushort_t)(r >> 16);
}

__device__ __forceinline__ void gload16(const void* g, void* s) {
  __builtin_amdgcn_global_load_lds((const __attribute__((address_space(1))) void*)g,
                                   (__attribute__((address_space(3))) void*)s, 16, 0, 0);
}

// C = A * B^T (+epilogue).  A: [M,K] bf16 row-major (lda), B: [N,K] bf16 row-major (ldb).
// EPI 0: outB = bf16(acc + bias?) (relu optional)
// EPI 1: outF = mask ? -1e9 : acc*scale   (scores)
// EPI 2: outF[row*ldc+col] += acc + bias  (fp32 residual accumulate)
template<int EPI>
__global__ __launch_bounds__(256, 2)
void gemm_bt(const ushort_t* __restrict__ A, const ushort_t* __restrict__ B,
             const float* __restrict__ bias, const int* __restrict__ mask,
             float* __restrict__ outF, ushort_t* __restrict__ outB,
             int M, int N, int K, int lda, int ldb, int ldc,
             long sAz, long sBz, long sCz,
             int headA, int headB, int headC, float scale, int relu)
{
  __shared__ ushort_t As[128 * 64];
  __shared__ ushort_t Bs[128 * 64];
  const int z = blockIdx.z;
  const long aOff = headA ? ((long)(z >> 3) * SS * lda + (long)(z & 7) * DKH) : (long)z * sAz;
  const long bOff = headB ? ((long)(z >> 3) * SS * ldb + (long)(z & 7) * DKH) : (long)z * sBz;
  const long cOff = headC ? ((long)(z >> 3) * SS * ldc + (long)(z & 7) * DKH) : (long)z * sCz;
  const ushort_t* Ab = A + aOff + (long)blockIdx.y * 128 * lda;
  const ushort_t* Bb = B + bOff + (long)blockIdx.x * 128 * ldb;
  const int tid = threadIdx.x, lane = tid & 63, wid = tid >> 6;
  const int wm = wid >> 1, wn = wid & 1;

  // staging: 4 chunks of 16B per thread per operand; LDS linear, source pre-swizzled
  const ushort_t* srcA[4]; const ushort_t* srcB[4];
  ushort_t* ldsA[4]; ushort_t* ldsB[4];
#pragma unroll
  for (int c = 0; c < 4; ++c) {
    int off = c * 4096 + tid * 16;          // byte offset in tile (128 rows x 128B)
    int row = off >> 7, colb = off & 127;
    int scol = (colb ^ ((row & 7) << 4)) >> 1;   // swizzled source column (elements)
    srcA[c] = Ab + (long)row * lda + scol;
    srcB[c] = Bb + (long)row * ldb + scol;
    int ub = c * 4096 + wid * 1024;         // wave-uniform LDS base
    ldsA[c] = (ushort_t*)((char*)As + ub);
    ldsB[c] = (ushort_t*)((char*)Bs + ub);
  }

  f32x4 acc[4][4] = {};

  for (int kt = 0; kt < K; kt += 64) {
#pragma unroll
    for (int c = 0; c < 4; ++c) gload16(srcA[c] + kt, ldsA[c]);
#pragma unroll
    for (int c = 0; c < 4; ++c) gload16(srcB[c] + kt, ldsB[c]);
    __syncthreads();
#pragma unroll
    for (int ks = 0; ks < 2; ++ks) {
      bf16x8 af[4], bfr[4];
      const int kb = ks * 64 + (lane >> 4) * 16;
#pragma unroll
      for (int f = 0; f < 4; ++f) {
        int ra = wm * 64 + f * 16 + (lane & 15);
        af[f]  = *(const bf16x8*)((const char*)As + ra * 128 + (kb ^ ((ra & 7) << 4)));
        int rb = wn * 64 + f * 16 + (lane & 15);
        bfr[f] = *(const bf16x8*)((const char*)Bs + rb * 128 + (kb ^ ((rb & 7) << 4)));
      }
#pragma unroll
      for (int i = 0; i < 4; ++i)
#pragma unroll
        for (int j = 0; j < 4; ++j)
          acc[i][j] = __builtin_amdgcn_mfma_f32_16x16x32_bf16(af[i], bfr[j], acc[i][j], 0, 0, 0);
    }
    __syncthreads();
  }

  const int row0 = blockIdx.y * 128 + wm * 64 + ((lane >> 4) << 2);
  const int col0 = blockIdx.x * 128 + wn * 64 + (lane & 15);
#pragma unroll
  for (int i = 0; i < 4; ++i) {
#pragma unroll
    for (int j = 0; j < 4; ++j) {
      const int col = col0 + j * 16;
      float bv = 0.f;
      if (EPI != 1) bv = bias ? bias[col] : 0.f;
#pragma unroll
      for (int r = 0; r < 4; ++r) {
        const int row = row0 + i * 16 + r;
        float v = acc[i][j][r];
        if (EPI == 0) {
          v += bv;
          if (relu) v = fmaxf(v, 0.f);
          outB[cOff + (long)row * ldc + col] = f2b(v);
        } else if (EPI == 1) {
          v *= scale;
          if (mask[(z >> 3) * SS + col]) v = -1e9f;
          outF[cOff + (long)row * ldc + col] = v;
        } else {
          outF[cOff + (long)row * ldc + col] += v + bv;
        }
      }
    }
  }
}

// x = data*sqrt(D) + pe + seg_emb[view_idx*S]
__global__ __launch_bounds__(256)
void build_x(const float* __restrict__ data, const float* __restrict__ seg,
             const int* __restrict__ viewp, float* __restrict__ x)
{
  int i = blockIdx.x * 256 + threadIdx.x;   // over 2048*512
  int d = i & 511;
  int s = (i >> 9) & 255;
  float ang = (float)s * exp2f((float)d * -0.03125f);  // S=2^8: S^(2d/D) = 2^(d/32)
  float pe = (d & 1) ? cosf(ang) : sinf(ang);
  int vrow = viewp[0] * SS;
  x[i] = data[i] * 22.627416997969522f + pe + seg[vrow * DIM + d];
}

// per-row LayerNorm (unbiased var, eps added to std). outB: bf16, else outF fp32.
__global__ __launch_bounds__(256)
void lnorm_k(const float* __restrict__ x, const float* __restrict__ alpha,
             const float* __restrict__ beta, ushort_t* __restrict__ outB,
             float* __restrict__ outF)
{
  const int row = blockIdx.x, tid = threadIdx.x;
  const float2* xr = (const float2*)(x + (long)row * DIM);
  float2 v = xr[tid];
  float s = v.x + v.y;
#pragma unroll
  for (int o = 32; o; o >>= 1) s += __shfl_xor(s, o, 64);
  __shared__ float rs[4], rq[4];
  if ((tid & 63) == 0) rs[tid >> 6] = s;
  __syncthreads();
  const float mu = (rs[0] + rs[1] + rs[2] + rs[3]) * (1.f / 512.f);
  const float dx = v.x - mu, dy = v.y - mu;
  float q = dx * dx + dy * dy;
#pragma unroll
  for (int o = 32; o; o >>= 1) q += __shfl_xor(q, o, 64);
  if ((tid & 63) == 0) rq[tid >> 6] = q;
  __syncthreads();
  const float var = (rq[0] + rq[1] + rq[2] + rq[3]) * (1.f / 511.f);
  const float rstd = 1.f / (sqrtf(var) + 1e-6f);
  const int d0 = tid * 2;
  const float o0 = alpha[d0] * dx * rstd + beta[d0];
  const float o1 = alpha[d0 + 1] * dy * rstd + beta[d0 + 1];
  if (outB) { outB[(long)row * DIM + d0] = f2b(o0); outB[(long)row * DIM + d0 + 1] = f2b(o1); }
  else      { outF[(long)row * DIM + d0] = o0;      outF[(long)row * DIM + d0 + 1] = o1; }
}

// softmax over rows of 256 (one wave per row, 4 rows per block), fp32 in -> bf16 out
__global__ __launch_bounds__(256)
void softmax_k(const float* __restrict__ sc, ushort_t* __restrict__ P)
{
  const int row = blockIdx.x * 4 + (threadIdx.x >> 6);
  const int lane = threadIdx.x & 63;
  float4 v = ((const float4*)(sc + (long)row * 256))[lane];
  float m = fmaxf(fmaxf(v.x, v.y), fmaxf(v.z, v.w));
#pragma unroll
  for (int o = 32; o; o >>= 1) m = fmaxf(m, __shfl_xor(m, o, 64));
  float e0 = __expf(v.x - m), e1 = __expf(v.y - m), e2 = __expf(v.z - m), e3 = __expf(v.w - m);
  float sum = e0 + e1 + e2 + e3;
#pragma unroll
  for (int o = 32; o; o >>= 1) sum += __shfl_xor(sum, o, 64);
  const float inv = 1.f / sum;
  u16x4 out; out.x = f2b(e0 * inv); out.y = f2b(e1 * inv); out.z = f2b(e2 * inv); out.w = f2b(e3 * inv);
  *(u16x4*)(P + (long)row * 256 + lane * 4) = out;
}

// fp32 [R,C] -> bf16 [C,R]  (per z matrix)
__global__ __launch_bounds__(256)
void wtrans(const float* __restrict__ in, ushort_t* __restrict__ out, int R, int C)
{
  __shared__ float t[32][33];
  const long zo = (long)blockIdx.z * R * C;
  const int c0 = blockIdx.x * 32, r0 = blockIdx.y * 32;
  const int tx = threadIdx.x & 31, ty = threadIdx.x >> 5;
#pragma unroll
  for (int i = 0; i < 4; ++i) t[ty + i * 8][tx] = in[zo + (long)(r0 + ty + i * 8) * C + c0 + tx];
  __syncthreads();
#pragma unroll
  for (int i = 0; i < 4; ++i) out[zo + (long)(c0 + ty + i * 8) * R + r0 + tx] = f2b(t[tx][ty + i * 8]);
}

// v [B,S,H,DK] bf16 -> vT [B,H,DK,S] bf16
__global__ __launch_bounds__(256)
void vtrans(const ushort_t* __restrict__ v, ushort_t* __restrict__ vT)
{
  __shared__ ushort_t t[32][33];
  const int z = blockIdx.z;                 // b*8+h
  const int b = z >> 3, h = z & 7;
  const int dk0 = blockIdx.x * 32, s0 = blockIdx.y * 32;
  const int tx = threadIdx.x & 31, ty = threadIdx.x >> 5;
#pragma unroll
  for (int i = 0; i < 4; ++i)
    t[ty + i * 8][tx] = v[(long)(b * 256 + s0 + ty + i * 8) * 2048 + h * 256 + dk0 + tx];
  __syncthreads();
#pragma unroll
  for (int i = 0; i < 4; ++i)
    vT[(long)z * 65536 + (long)(dk0 + ty + i * 8) * 256 + s0 + tx] = t[tx][ty + i * 8];
}

extern "C" void kernel_launch(void* const* d_in, const int* in_sizes, int n_in,
                              void* d_out, int out_size, void* d_ws, size_t ws_size,
                              hipStream_t stream)
{
  const float* data  = (const float*)d_in[0];
  const int*   attnm = (const int*)d_in[1];
  const int*   viewp = (const int*)d_in[2];
  const float* seg   = (const float*)d_in[3];
  const float* Wq    = (const float*)d_in[4];
  const float* bq    = (const float*)d_in[5];
  const float* Wk    = (const float*)d_in[6];
  const float* bk    = (const float*)d_in[7];
  const float* Wv    = (const float*)d_in[8];
  const float* bv    = (const float*)d_in[9];
  const float* Wo    = (const float*)d_in[10];
  const float* bo    = (const float*)d_in[11];
  const float* W1    = (const float*)d_in[12];
  const float* b1    = (const float*)d_in[13];
  const float* W2    = (const float*)d_in[14];
  const float* b2    = (const float*)d_in[15];
  const float* al1   = (const float*)d_in[16];
  const float* be1   = (const float*)d_in[17];
  const float* al2   = (const float*)d_in[18];
  const float* be2   = (const float*)d_in[19];
  const float* alf   = (const float*)d_in[20];
  const float* bef   = (const float*)d_in[21];

  char* w = (char*)d_ws;
  const size_t MB = 1024 * 1024;
  ushort_t* WqT = (ushort_t*)(w + 0 * MB);    // [L][2048][512] bf16
  ushort_t* WkT = (ushort_t*)(w + 8 * MB);
  ushort_t* WvT = (ushort_t*)(w + 16 * MB);
  ushort_t* WoT = (ushort_t*)(w + 24 * MB);   // [L][512][2048]
  ushort_t* W1T = (ushort_t*)(w + 32 * MB);   // [L][2048][512]
  ushort_t* W2T = (ushort_t*)(w + 40 * MB);   // [L][512][2048]
  float*    x   = (float*)   (w + 48 * MB);   // [2048][512] fp32
  ushort_t* x2  = (ushort_t*)(w + 52 * MB);   // [2048][512] bf16
  ushort_t* qb  = (ushort_t*)(w + 54 * MB);   // [2048][2048] bf16
  ushort_t* kbf = (ushort_t*)(w + 62 * MB);
  ushort_t* vb  = (ushort_t*)(w + 70 * MB);
  ushort_t* vT  = (ushort_t*)(w + 78 * MB);   // [64][256][256]
  float*    sc  = (float*)   (w + 86 * MB);   // [64][256][256] fp32
  ushort_t* P   = (ushort_t*)(w + 102 * MB);  // [64][256][256] bf16
  ushort_t* ao  = (ushort_t*)(w + 110 * MB);  // [2048][2048] bf16
  ushort_t* ffh = (ushort_t*)(w + 118 * MB);  // [2048][2048] bf16  (end: 126MB)

  dim3 blk(256);
  wtrans<<<dim3(64, 16, 4), blk, 0, stream>>>(Wq, WqT, 512, 2048);
  wtrans<<<dim3(64, 16, 4), blk, 0, stream>>>(Wk, WkT, 512, 2048);
  wtrans<<<dim3(64, 16, 4), blk, 0, stream>>>(Wv, WvT, 512, 2048);
  wtrans<<<dim3(16, 64, 4), blk, 0, stream>>>(Wo, WoT, 2048, 512);
  wtrans<<<dim3(64, 16, 4), blk, 0, stream>>>(W1, W1T, 512, 2048);
  wtrans<<<dim3(16, 64, 4), blk, 0, stream>>>(W2, W2T, 2048, 512);
  build_x<<<4096, blk, 0, stream>>>(data, seg, viewp, x);

  for (int i = 0; i < LNUM; ++i) {
    lnorm_k<<<2048, blk, 0, stream>>>(x, al1 + i * 512, be1 + i * 512, x2, nullptr);
    gemm_bt<0><<<dim3(16, 16, 1), blk, 0, stream>>>(x2, WqT + (size_t)i * HDD * DIM, bq + i * 2048,
        nullptr, nullptr, qb, 2048, 2048, 512, 512, 512, 2048, 0, 0, 0, 0, 0, 0, 0.f, 0);
    gemm_bt<0><<<dim3(16, 16, 1), blk, 0, stream>>>(x2, WkT + (size_t)i * HDD * DIM, bk + i * 2048,
        nullptr, nullptr, kbf, 2048, 2048, 512, 512, 512, 2048, 0, 0, 0, 0, 0, 0, 0.f, 0);
    gemm_bt<0><<<dim3(16, 16, 1), blk, 0, stream>>>(x2, WvT + (size_t)i * HDD * DIM, bv + i * 2048,
        nullptr, nullptr, vb, 2048, 2048, 512, 512, 512, 2048, 0, 0, 0, 0, 0, 0, 0.f, 0);
    vtrans<<<dim3(8, 8, 64), blk, 0, stream>>>(vb, vT);
    gemm_bt<1><<<dim3(2, 2, 64), blk, 0, stream>>>(qb, kbf, nullptr, attnm, sc, nullptr,
        256, 256, 256, 2048, 2048, 256, 0, 0, 65536, 1, 1, 0, 0.0625f, 0);
    softmax_k<<<4096, blk, 0, stream>>>(sc, P);
    gemm_bt<0><<<dim3(2, 2, 64), blk, 0, stream>>>(P, vT, nullptr, nullptr, nullptr, ao,
        256, 256, 256, 256, 256, 2048, 65536, 65536, 0, 0, 0, 1, 0.f, 0);
    gemm_bt<2><<<dim3(4, 16, 1), blk, 0, stream>>>(ao, WoT + (size_t)i * DIM * HDD, bo + i * 512,
        nullptr, x, nullptr, 2048, 512, 2048, 2048, 2048, 512, 0, 0, 0, 0, 0, 0, 0.f, 0);
    lnorm_k<<<2048, blk, 0, stream>>>(x, al2 + i * 512, be2 + i * 512, x2, nullptr);
    gemm_bt<0><<<dim3(16, 16, 1), blk, 0, stream>>>(x2, W1T + (size_t)i * DFFN * DIM, b1 + i * 2048,
        nullptr, nullptr, ffh, 2048, 2048, 512, 512, 512, 2048, 0, 0, 0, 0, 0, 0, 0.f, 1);
    gemm_bt<2><<<dim3(4, 16, 1), blk, 0, stream>>>(ffh, W2T + (size_t)i * DIM * DFFN, b2 + i * 512,
        nullptr, x, nullptr, 2048, 512, 2048, 2048, 2048, 512, 0, 0, 0, 0, 0, 0, 0.f, 0);
  }
  lnorm_k<<<2048, blk, 0, stream>>>(x, alf, bef, nullptr, (float*)d_out);
}

// Round 2
// 452.413 us; speedup vs baseline: 1.7535x; 1.7535x over previous
//
#include <hip/hip_runtime.h>
#include <hip/hip_bf16.h>

#define LNUM 4
#define DIM  512
#define SS   256

typedef unsigned short ushort_t;
typedef __attribute__((ext_vector_type(8))) short bf16x8;
typedef __attribute__((ext_vector_type(4))) float f32x4;

__device__ __forceinline__ ushort_t f2b(float f) {
  union { float f; unsigned u; } x; x.f = f;
  unsigned r = x.u + 0x7FFFu + ((x.u >> 16) & 1u);
  return (ushort_t)(r >> 16);
}

__device__ __forceinline__ void gload16(const void* g, void* s) {
  __builtin_amdgcn_global_load_lds((const __attribute__((address_space(1))) void*)g,
                                   (__attribute__((address_space(3))) void*)s, 16, 0, 0);
}

// ---------------------------------------------------------------------------
// C = A * B^T, 2-phase double-buffered LDS pipeline, XOR-swizzled LDS.
// EPI 0: outB = bf16(acc + bias) [relu opt]
// EPI 2: atomicAdd(outF, acc + bias(kz==0))   (split-K residual accumulate)
// EPI 3: fused QKV routing (seg by col block) -> outB/outB2/outB3 bf16
// ---------------------------------------------------------------------------
template<int TM, int TN, int EPI>
__global__ __launch_bounds__(256, 2)
void gemm_bt(const ushort_t* __restrict__ A, const ushort_t* __restrict__ B,
             const float* __restrict__ bias, const float* __restrict__ bias2,
             const float* __restrict__ bias3,
             ushort_t* __restrict__ outB, ushort_t* __restrict__ outB2,
             ushort_t* __restrict__ outB3, float* __restrict__ outF,
             int K, int lda, int ldb, int ldc, int nkz, int relu)
{
  constexpr int CA = TM / 32, CB = TN / 32, WM = TM / 32, WN = TN / 32;
  __shared__ ushort_t As[2 * TM * 64];
  __shared__ ushort_t Bs[2 * TN * 64];
  const int tid = threadIdx.x, lane = tid & 63, wid = tid >> 6;
  const int wm = wid >> 1, wn = wid & 1;
  const int kz = blockIdx.z, Kz = K / nkz, k0 = kz * Kz, nt = Kz >> 6;

  const ushort_t* Ab = A + (long)blockIdx.y * TM * lda + k0;
  const ushort_t* Bb = B + (long)blockIdx.x * TN * ldb + k0;

  const ushort_t* srcA[CA]; ushort_t* ldsA[CA];
  const ushort_t* srcB[CB]; ushort_t* ldsB[CB];
#pragma unroll
  for (int c = 0; c < CA; ++c) {
    int off = c * 4096 + tid * 16;
    int row = off >> 7;
    int scol = ((off & 127) ^ ((row & 7) << 4)) >> 1;
    srcA[c] = Ab + (long)row * lda + scol;
    ldsA[c] = As + c * 2048 + wid * 512;
  }
#pragma unroll
  for (int c = 0; c < CB; ++c) {
    int off = c * 4096 + tid * 16;
    int row = off >> 7;
    int scol = ((off & 127) ^ ((row & 7) << 4)) >> 1;
    srcB[c] = Bb + (long)row * ldb + scol;
    ldsB[c] = Bs + c * 2048 + wid * 512;
  }

  f32x4 acc[WM][WN] = {};

  auto STAGE = [&](int buf, int t) {
#pragma unroll
    for (int c = 0; c < CA; ++c) gload16(srcA[c] + t * 64, ldsA[c] + buf * TM * 64);
#pragma unroll
    for (int c = 0; c < CB; ++c) gload16(srcB[c] + t * 64, ldsB[c] + buf * TN * 64);
  };

  STAGE(0, 0);
  __syncthreads();
  for (int t = 0; t < nt; ++t) {
    if (t + 1 < nt) STAGE((t + 1) & 1, t + 1);
    const int buf = t & 1;
#pragma unroll
    for (int ks = 0; ks < 2; ++ks) {
      const int kb = ks * 64 + ((lane >> 4) << 4);
      bf16x8 af[WM], bfr[WN];
#pragma unroll
      for (int f = 0; f < WM; ++f) {
        int ra = wm * (TM / 2) + f * 16 + (lane & 15);
        af[f] = *(const bf16x8*)((const char*)As + buf * TM * 128 + ra * 128 + (kb ^ ((ra & 7) << 4)));
      }
#pragma unroll
      for (int g = 0; g < WN; ++g) {
        int rb = wn * (TN / 2) + g * 16 + (lane & 15);
        bfr[g] = *(const bf16x8*)((const char*)Bs + buf * TN * 128 + rb * 128 + (kb ^ ((rb & 7) << 4)));
      }
#pragma unroll
      for (int i = 0; i < WM; ++i)
#pragma unroll
        for (int j = 0; j < WN; ++j)
          acc[i][j] = __builtin_amdgcn_mfma_f32_16x16x32_bf16(af[i], bfr[j], acc[i][j], 0, 0, 0);
    }
    __syncthreads();
  }

  const int row0 = blockIdx.y * TM + wm * (TM / 2) + ((lane >> 4) << 2);
  int col0 = blockIdx.x * TN + wn * (TN / 2) + (lane & 15);
  const float* bsel = bias;
  ushort_t* osel = outB;
  if (EPI == 3) {
    int seg = (blockIdx.x * TN) >> 11;
    if (seg == 1) { bsel = bias2; osel = outB2; }
    else if (seg == 2) { bsel = bias3; osel = outB3; }
    col0 -= seg * 2048;
  }
#pragma unroll
  for (int i = 0; i < WM; ++i) {
#pragma unroll
    for (int j = 0; j < WN; ++j) {
      const int col = col0 + j * 16;
      float bv;
      if (EPI == 2) bv = (kz == 0) ? bias[col] : 0.f;
      else          bv = bsel[col];
#pragma unroll
      for (int r = 0; r < 4; ++r) {
        const int row = row0 + i * 16 + r;
        float v = acc[i][j][r];
        if (EPI == 2) {
          atomicAdd(outF + (long)row * ldc + col, v + bv);
        } else {
          v += bv;
          if (relu) v = fmaxf(v, 0.f);
          osel[(long)row * ldc + col] = f2b(v);
        }
      }
    }
  }
}

// ---------------------------------------------------------------------------
// Fused flash attention: one block per (q-tile of 64, b*8+h).
// Q-tile in LDS; stream K chunks -> scores in regs -> wave softmax ->
// P in LDS -> stream vT chunks -> O written bf16.
// ---------------------------------------------------------------------------
__global__ __launch_bounds__(256)
void attn_k(const ushort_t* __restrict__ qb, const ushort_t* __restrict__ kbf,
            const ushort_t* __restrict__ vT, const int* __restrict__ attnm,
            ushort_t* __restrict__ ao)
{
  __shared__ ushort_t Qs[64 * 256];
  __shared__ ushort_t Ps[64 * 256];
  __shared__ ushort_t KVs[2 * 64 * 256];
  __shared__ int smask[256];
  const int qt = blockIdx.x, bh = blockIdx.y, b = bh >> 3, h = bh & 7;
  const int tid = threadIdx.x, lane = tid & 63, wid = tid >> 6;
  smask[tid] = attnm[b * 256 + tid];

  int srow[8], scol[8];
#pragma unroll
  for (int c = 0; c < 8; ++c) {
    int off = c * 4096 + tid * 16;
    srow[c] = off >> 9;
    scol[c] = ((off & 511) ^ ((srow[c] & 7) << 4)) >> 1;
  }

  const ushort_t* qsrc = qb + (long)(b * 256 + qt * 64) * 2048 + h * 256;
#pragma unroll
  for (int c = 0; c < 8; ++c)
    gload16(qsrc + (long)srow[c] * 2048 + scol[c], Qs + c * 2048 + wid * 512);

  auto stageK = [&](int kc, int buf) {
#pragma unroll
    for (int c = 0; c < 8; ++c)
      gload16(kbf + (long)(b * 256 + kc * 64 + srow[c]) * 2048 + h * 256 + scol[c],
              KVs + buf * 16384 + c * 2048 + wid * 512);
  };
  auto stageV = [&](int vc, int buf) {
#pragma unroll
    for (int c = 0; c < 8; ++c)
      gload16(vT + (long)bh * 65536 + (long)(vc * 64 + srow[c]) * 256 + scol[c],
              KVs + buf * 16384 + c * 2048 + wid * 512);
  };

  f32x4 accs[16] = {};
  stageK(0, 0);
  __syncthreads();

#pragma unroll
  for (int kc = 0; kc < 4; ++kc) {
    if (kc < 3) stageK(kc + 1, (kc + 1) & 1);
    else        stageV(0, 0);
#pragma unroll
    for (int ks = 0; ks < 8; ++ks) {
      const int kb = ks * 64 + ((lane >> 4) << 4);
      const int ra = wid * 16 + (lane & 15);
      bf16x8 aq = *(const bf16x8*)((const char*)Qs + ra * 512 + (kb ^ ((ra & 7) << 4)));
#pragma unroll
      for (int j = 0; j < 4; ++j) {
        int rb = j * 16 + (lane & 15);
        bf16x8 bk_ = *(const bf16x8*)((const char*)KVs + (kc & 1) * 32768 + rb * 512 + (kb ^ ((rb & 7) << 4)));
        accs[kc * 4 + j] = __builtin_amdgcn_mfma_f32_16x16x32_bf16(aq, bk_, accs[kc * 4 + j], 0, 0, 0);
      }
    }
    __syncthreads();
  }

  // softmax over 256 keys per q-row; lane holds 16 cols x 4 rows
  float mr[4] = {-3e38f, -3e38f, -3e38f, -3e38f}, sr[4] = {};
#pragma unroll
  for (int jj = 0; jj < 16; ++jj) {
    int key = jj * 16 + (lane & 15);
    bool mk = smask[key] != 0;
#pragma unroll
    for (int r = 0; r < 4; ++r) {
      float s = mk ? -1e9f : accs[jj][r] * 0.0625f;
      accs[jj][r] = s;
      mr[r] = fmaxf(mr[r], s);
    }
  }
#pragma unroll
  for (int o = 1; o < 16; o <<= 1)
#pragma unroll
    for (int r = 0; r < 4; ++r) mr[r] = fmaxf(mr[r], __shfl_xor(mr[r], o, 64));
#pragma unroll
  for (int jj = 0; jj < 16; ++jj)
#pragma unroll
    for (int r = 0; r < 4; ++r) {
      float e = __expf(accs[jj][r] - mr[r]);
      accs[jj][r] = e;
      sr[r] += e;
    }
#pragma unroll
  for (int o = 1; o < 16; o <<= 1)
#pragma unroll
    for (int r = 0; r < 4; ++r) sr[r] += __shfl_xor(sr[r], o, 64);
#pragma unroll
  for (int r = 0; r < 4; ++r) sr[r] = 1.f / sr[r];

#pragma unroll
  for (int jj = 0; jj < 16; ++jj)
#pragma unroll
    for (int r = 0; r < 4; ++r) {
      int prow = wid * 16 + ((lane >> 4) << 2) + r;
      int cb = (jj * 16 + (lane & 15)) * 2;
      *(ushort_t*)((char*)Ps + prow * 512 + (cb ^ ((prow & 7) << 4))) = f2b(accs[jj][r] * sr[r]);
    }
  __syncthreads();

#pragma unroll
  for (int vc = 0; vc < 4; ++vc) {
    if (vc < 3) stageV(vc + 1, (vc + 1) & 1);
    f32x4 acco[4] = {};
#pragma unroll
    for (int ks = 0; ks < 8; ++ks) {
      const int kb = ks * 64 + ((lane >> 4) << 4);
      const int ra = wid * 16 + (lane & 15);
      bf16x8 pa = *(const bf16x8*)((const char*)Ps + ra * 512 + (kb ^ ((ra & 7) << 4)));
#pragma unroll
      for (int j = 0; j < 4; ++j) {
        int rb = j * 16 + (lane & 15);
        bf16x8 bv_ = *(const bf16x8*)((const char*)KVs + (vc & 1) * 32768 + rb * 512 + (kb ^ ((rb & 7) << 4)));
        acco[j] = __builtin_amdgcn_mfma_f32_16x16x32_bf16(pa, bv_, acco[j], 0, 0, 0);
      }
    }
    __syncthreads();
#pragma unroll
    for (int j = 0; j < 4; ++j)
#pragma unroll
      for (int r = 0; r < 4; ++r) {
        int q = qt * 64 + wid * 16 + ((lane >> 4) << 2) + r;
        int dk = vc * 64 + j * 16 + (lane & 15);
        ao[(long)(b * 256 + q) * 2048 + h * 256 + dk] = f2b(acco[j][r]);
      }
  }
}

// x = data*sqrt(D) + pe + seg_emb[view_idx*S]
__global__ __launch_bounds__(256)
void build_x(const float* __restrict__ data, const float* __restrict__ seg,
             const int* __restrict__ viewp, float* __restrict__ x)
{
  int i = blockIdx.x * 256 + threadIdx.x;
  int d = i & 511;
  int s = (i >> 9) & 255;
  float ang = (float)s * exp2f((float)d * -0.03125f);
  float pe = (d & 1) ? cosf(ang) : sinf(ang);
  int vrow = viewp[0] * SS;
  x[i] = data[i] * 22.627416997969522f + pe + seg[vrow * DIM + d];
}

// per-row LayerNorm (unbiased var, eps added to std)
__global__ __launch_bounds__(256)
void lnorm_k(const float* __restrict__ x, const float* __restrict__ alpha,
             const float* __restrict__ beta, ushort_t* __restrict__ outB,
             float* __restrict__ outF)
{
  const int row = blockIdx.x, tid = threadIdx.x;
  const float2* xr = (const float2*)(x + (long)row * DIM);
  float2 v = xr[tid];
  float s = v.x + v.y;
#pragma unroll
  for (int o = 32; o; o >>= 1) s += __shfl_xor(s, o, 64);
  __shared__ float rs[4], rq[4];
  if ((tid & 63) == 0) rs[tid >> 6] = s;
  __syncthreads();
  const float mu = (rs[0] + rs[1] + rs[2] + rs[3]) * (1.f / 512.f);
  const float dx = v.x - mu, dy = v.y - mu;
  float q = dx * dx + dy * dy;
#pragma unroll
  for (int o = 32; o; o >>= 1) q += __shfl_xor(q, o, 64);
  if ((tid & 63) == 0) rq[tid >> 6] = q;
  __syncthreads();
  const float var = (rq[0] + rq[1] + rq[2] + rq[3]) * (1.f / 511.f);
  const float rstd = 1.f / (sqrtf(var) + 1e-6f);
  const int d0 = tid * 2;
  const float o0 = alpha[d0] * dx * rstd + beta[d0];
  const float o1 = alpha[d0 + 1] * dy * rstd + beta[d0 + 1];
  if (outB) { outB[(long)row * DIM + d0] = f2b(o0); outB[(long)row * DIM + d0 + 1] = f2b(o1); }
  else      { outF[(long)row * DIM + d0] = o0;      outF[(long)row * DIM + d0 + 1] = o1; }
}

// fp32 [R,C] -> bf16 [C,R], per-z with output z-stride (elements)
__global__ __launch_bounds__(256)
void wtrans(const float* __restrict__ in, ushort_t* __restrict__ out,
            int R, int C, long ozs)
{
  __shared__ float t[32][33];
  const int z = blockIdx.z;
  const long zi = (long)z * R * C, zo = (long)z * ozs;
  const int c0 = blockIdx.x * 32, r0 = blockIdx.y * 32;
  const int tx = threadIdx.x & 31, ty = threadIdx.x >> 5;
#pragma unroll
  for (int i = 0; i < 4; ++i) t[ty + i * 8][tx] = in[zi + (long)(r0 + ty + i * 8) * C + c0 + tx];
  __syncthreads();
#pragma unroll
  for (int i = 0; i < 4; ++i) out[zo + (long)(c0 + ty + i * 8) * R + r0 + tx] = f2b(t[tx][ty + i * 8]);
}

// v [B,S,H*DK] bf16 -> vT [B*H][DK][S] bf16
__global__ __launch_bounds__(256)
void vtrans(const ushort_t* __restrict__ v, ushort_t* __restrict__ vT)
{
  __shared__ ushort_t t[32][33];
  const int z = blockIdx.z;
  const int b = z >> 3, h = z & 7;
  const int dk0 = blockIdx.x * 32, s0 = blockIdx.y * 32;
  const int tx = threadIdx.x & 31, ty = threadIdx.x >> 5;
#pragma unroll
  for (int i = 0; i < 4; ++i)
    t[ty + i * 8][tx] = v[(long)(b * 256 + s0 + ty + i * 8) * 2048 + h * 256 + dk0 + tx];
  __syncthreads();
#pragma unroll
  for (int i = 0; i < 4; ++i)
    vT[(long)z * 65536 + (long)(dk0 + ty + i * 8) * 256 + s0 + tx] = t[tx][ty + i * 8];
}

extern "C" void kernel_launch(void* const* d_in, const int* in_sizes, int n_in,
                              void* d_out, int out_size, void* d_ws, size_t ws_size,
                              hipStream_t stream)
{
  const float* data  = (const float*)d_in[0];
  const int*   attnm = (const int*)d_in[1];
  const int*   viewp = (const int*)d_in[2];
  const float* seg   = (const float*)d_in[3];
  const float* Wq    = (const float*)d_in[4];
  const float* bq    = (const float*)d_in[5];
  const float* Wk    = (const float*)d_in[6];
  const float* bk    = (const float*)d_in[7];
  const float* Wv    = (const float*)d_in[8];
  const float* bv    = (const float*)d_in[9];
  const float* Wo    = (const float*)d_in[10];
  const float* bo    = (const float*)d_in[11];
  const float* W1    = (const float*)d_in[12];
  const float* b1    = (const float*)d_in[13];
  const float* W2    = (const float*)d_in[14];
  const float* b2    = (const float*)d_in[15];
  const float* al1   = (const float*)d_in[16];
  const float* be1   = (const float*)d_in[17];
  const float* al2   = (const float*)d_in[18];
  const float* be2   = (const float*)d_in[19];
  const float* alf   = (const float*)d_in[20];
  const float* bef   = (const float*)d_in[21];

  char* w = (char*)d_ws;
  const size_t MB = 1024 * 1024;
  ushort_t* qkvW = (ushort_t*)(w + 0 * MB);   // [L][6144][512] bf16 (24MB)
  ushort_t* WoT  = (ushort_t*)(w + 24 * MB);  // [L][512][2048]
  ushort_t* W1T  = (ushort_t*)(w + 32 * MB);  // [L][2048][512]
  ushort_t* W2T  = (ushort_t*)(w + 40 * MB);  // [L][512][2048]
  float*    x    = (float*)   (w + 48 * MB);  // [2048][512] fp32
  ushort_t* x2   = (ushort_t*)(w + 52 * MB);  // [2048][512] bf16
  ushort_t* qb   = (ushort_t*)(w + 54 * MB);  // [2048][2048] bf16
  ushort_t* kbf  = (ushort_t*)(w + 62 * MB);
  ushort_t* vb   = (ushort_t*)(w + 70 * MB);
  ushort_t* vT   = (ushort_t*)(w + 78 * MB);  // [64][256][256]
  ushort_t* ao   = (ushort_t*)(w + 86 * MB);  // [2048][2048]
  ushort_t* ffh  = (ushort_t*)(w + 94 * MB);  // [2048][2048] (end 102MB)

  dim3 blk(256);
  const long QKV_L = 6144L * 512;
  wtrans<<<dim3(64, 16, 4), blk, 0, stream>>>(Wq, qkvW + 0 * 2048 * 512, 512, 2048, QKV_L);
  wtrans<<<dim3(64, 16, 4), blk, 0, stream>>>(Wk, qkvW + 1 * 2048 * 512, 512, 2048, QKV_L);
  wtrans<<<dim3(64, 16, 4), blk, 0, stream>>>(Wv, qkvW + 2 * 2048 * 512, 512, 2048, QKV_L);
  wtrans<<<dim3(16, 64, 4), blk, 0, stream>>>(Wo, WoT, 2048, 512, 512L * 2048);
  wtrans<<<dim3(64, 16, 4), blk, 0, stream>>>(W1, W1T, 512, 2048, 2048L * 512);
  wtrans<<<dim3(16, 64, 4), blk, 0, stream>>>(W2, W2T, 2048, 512, 512L * 2048);
  build_x<<<4096, blk, 0, stream>>>(data, seg, viewp, x);

  for (int i = 0; i < LNUM; ++i) {
    lnorm_k<<<2048, blk, 0, stream>>>(x, al1 + i * 512, be1 + i * 512, x2, nullptr);
    // fused QKV: [2048,512] x [6144,512]^T
    gemm_bt<128, 128, 3><<<dim3(48, 16, 1), blk, 0, stream>>>(
        x2, qkvW + (long)i * QKV_L, bq + i * 2048, bk + i * 2048, bv + i * 2048,
        qb, kbf, vb, nullptr, 512, 512, 512, 2048, 1, 0);
    vtrans<<<dim3(8, 8, 64), blk, 0, stream>>>(vb, vT);
    attn_k<<<dim3(4, 64), blk, 0, stream>>>(qb, kbf, vT, attnm, ao);
    // Wo: [2048,2048] x [512,2048]^T, split-K=2, += into x
    gemm_bt<64, 64, 2><<<dim3(8, 32, 2), blk, 0, stream>>>(
        ao, WoT + (long)i * 512 * 2048, bo + i * 512, nullptr, nullptr,
        nullptr, nullptr, nullptr, x, 2048, 2048, 2048, 512, 2, 0);
    lnorm_k<<<2048, blk, 0, stream>>>(x, al2 + i * 512, be2 + i * 512, x2, nullptr);
    // FF1: [2048,512] x [2048,512]^T, relu
    gemm_bt<128, 64, 0><<<dim3(32, 16, 1), blk, 0, stream>>>(
        x2, W1T + (long)i * 2048 * 512, b1 + i * 2048, nullptr, nullptr,
        ffh, nullptr, nullptr, nullptr, 512, 512, 512, 2048, 1, 1);
    // FF2: [2048,2048] x [512,2048]^T, split-K=2, += into x
    gemm_bt<64, 64, 2><<<dim3(8, 32, 2), blk, 0, stream>>>(
        ffh, W2T + (long)i * 512 * 2048, b2 + i * 512, nullptr, nullptr,
        nullptr, nullptr, nullptr, x, 2048, 2048, 2048, 512, 2, 0);
  }
  lnorm_k<<<2048, blk, 0, stream>>>(x, alf, bef, nullptr, (float*)d_out);
}